// Round 3
// baseline (203.897 us; speedup 1.0000x reference)
//
#include <hip/hip_runtime.h>
#include <hip/hip_bf16.h>

#define N_NODES 100000
#define N_EDGES 1600000
#define D_FEAT  64

// Fused wave-per-node aggregate. No workspace, no inter-kernel dependency:
// each wave (64 lanes) owns one output node.
//   1) dual binary search over sorted seg_ids gives the node's edge range
//      [s, e): s = lower_bound(node), e = lower_bound(node+1). Both chains
//      are independent (2 loads in flight), wave-uniform address (broadcast).
//   2) gather: sub = lane>>4 (edge slot 0..3), chunk = lane&15 (float4 of the
//      row). Unroll 2 -> 8 gathers in flight. Tail handled branch-free by
//      clamped index + 0/1-mask FMA.
//   3) cross-subgroup reduce via shfl_xor(16,32); lanes 0-15 store 256B.
// Pure reads of d_in, disjoint writes of d_out, no atomics -> bit-identical
// on every replay.
__global__ __launch_bounds__(256) void fused_aggregate_kernel(
        const float* __restrict__ feat,
        const int* __restrict__ neigh_idx,
        const int* __restrict__ seg_ids,
        float* __restrict__ out) {
    int node  = blockIdx.x * 4 + (threadIdx.x >> 6);   // wave-uniform
    int lane  = threadIdx.x & 63;
    int sub   = lane >> 4;
    int chunk = lane & 15;

    // lower_bound(node) and lower_bound(node+1), interleaved.
    // 2^21 > N_EDGES, so 21 iterations always converge.
    int lo0 = 0, hi0 = N_EDGES;
    int lo1 = 0, hi1 = N_EDGES;
    #pragma unroll 1
    for (int it = 0; it < 21; ++it) {
        if (lo0 < hi0) {
            int m = (lo0 + hi0) >> 1;
            if (seg_ids[m] < node) lo0 = m + 1; else hi0 = m;
        }
        if (lo1 < hi1) {
            int m = (lo1 + hi1) >> 1;
            if (seg_ids[m] < node + 1) lo1 = m + 1; else hi1 = m;
        }
    }
    int s = lo0;
    int e = lo1;

    float4 acc0 = make_float4(0.f, 0.f, 0.f, 0.f);
    float4 acc1 = make_float4(0.f, 0.f, 0.f, 0.f);

    for (int base = s; base < e; base += 8) {
        int i0 = base + sub;
        int i1 = i0 + 4;
        int c0 = (i0 < e) ? i0 : (e - 1);   // e > s here, so e-1 >= s valid
        int c1 = (i1 < e) ? i1 : (e - 1);
        float m0 = (i0 < e) ? 1.f : 0.f;
        float m1 = (i1 < e) ? 1.f : 0.f;
        int n0 = neigh_idx[c0];
        int n1 = neigh_idx[c1];
        const float4* r0 = reinterpret_cast<const float4*>(feat + (size_t)n0 * D_FEAT);
        const float4* r1 = reinterpret_cast<const float4*>(feat + (size_t)n1 * D_FEAT);
        float4 v0 = r0[chunk];
        float4 v1 = r1[chunk];
        acc0.x = fmaf(m0, v0.x, acc0.x);
        acc0.y = fmaf(m0, v0.y, acc0.y);
        acc0.z = fmaf(m0, v0.z, acc0.z);
        acc0.w = fmaf(m0, v0.w, acc0.w);
        acc1.x = fmaf(m1, v1.x, acc1.x);
        acc1.y = fmaf(m1, v1.y, acc1.y);
        acc1.z = fmaf(m1, v1.z, acc1.z);
        acc1.w = fmaf(m1, v1.w, acc1.w);
    }

    float4 acc;
    acc.x = acc0.x + acc1.x;
    acc.y = acc0.y + acc1.y;
    acc.z = acc0.z + acc1.z;
    acc.w = acc0.w + acc1.w;

    // reduce across the 4 subgroups (lanes l, l^16, l^32, l^48)
    acc.x += __shfl_xor(acc.x, 16);
    acc.y += __shfl_xor(acc.y, 16);
    acc.z += __shfl_xor(acc.z, 16);
    acc.w += __shfl_xor(acc.w, 16);
    acc.x += __shfl_xor(acc.x, 32);
    acc.y += __shfl_xor(acc.y, 32);
    acc.z += __shfl_xor(acc.z, 32);
    acc.w += __shfl_xor(acc.w, 32);

    if (lane < 16) {
        reinterpret_cast<float4*>(out + (size_t)node * D_FEAT)[chunk] = acc;
    }
}

extern "C" void kernel_launch(void* const* d_in, const int* in_sizes, int n_in,
                              void* d_out, int out_size, void* d_ws, size_t ws_size,
                              hipStream_t stream) {
    const float* features  = (const float*)d_in[0];
    const int*   neigh_idx = (const int*)d_in[1];
    const int*   seg_ids   = (const int*)d_in[2];
    float*       out       = (float*)d_out;
    (void)d_ws; (void)ws_size;

    int block = 256;                 // 4 waves = 4 nodes per block
    int grid  = (N_NODES + 3) / 4;   // N_NODES % 4 == 0 -> no partial waves
    fused_aggregate_kernel<<<grid, block, 0, stream>>>(features, neigh_idx, seg_ids, out);
}

// Round 4
// 66.243 us; speedup vs baseline: 3.0780x; 3.0780x over previous
//
#include <hip/hip_runtime.h>
#include <hip/hip_bf16.h>

#define N_NODES 100000
#define N_EDGES 1600000
#define D_FEAT  64

// Kernel 1 (VERBATIM round-1 version, end-to-end proven): offsets[n] = first
// edge index i with seg_ids[i] >= n. offsets[N_NODES] = N_EDGES falls out
// naturally (all ids < N_NODES). One thread per output entry, coalesced write.
__global__ void seg_offsets_kernel(const int* __restrict__ seg_ids,
                                   int* __restrict__ offsets) {
    int n = blockIdx.x * blockDim.x + threadIdx.x;
    if (n > N_NODES) return;
    int lo = 0, hi = N_EDGES;
    while (lo < hi) {
        int mid = (lo + hi) >> 1;
        if (seg_ids[mid] < n) lo = mid + 1; else hi = mid;
    }
    offsets[n] = lo;
}

// Kernel 2: wave-per-node, 16 edges in flight.
//   sub   = lane>>4 (0..3): edge slot within a group of 4
//   chunk = lane&15       : which float4 of the 64-float row
// Unroll 4 over edge groups -> 16 independent gathers in flight per wave.
// Avg segment length is 16 (Poisson), so most waves need ONE outer iteration.
// Tail is branch-free: clamped index + 0/1-mask FMA. Cross-subgroup reduce via
// shfl_xor(16,32); lanes 0-15 do one coalesced 256B store. No atomics ->
// deterministic across replays.
__global__ __launch_bounds__(256) void aggregate_kernel(
        const float* __restrict__ feat,
        const int* __restrict__ neigh_idx,
        const int* __restrict__ offsets,
        float* __restrict__ out) {
    int node  = blockIdx.x * 4 + (threadIdx.x >> 6);   // wave-uniform
    if (node >= N_NODES) return;
    int lane  = threadIdx.x & 63;
    int sub   = lane >> 4;
    int chunk = lane & 15;

    int s = offsets[node];
    int e = offsets[node + 1];

    float4 a0 = make_float4(0.f, 0.f, 0.f, 0.f);
    float4 a1 = make_float4(0.f, 0.f, 0.f, 0.f);
    float4 a2 = make_float4(0.f, 0.f, 0.f, 0.f);
    float4 a3 = make_float4(0.f, 0.f, 0.f, 0.f);

    for (int base = s; base < e; base += 16) {
        int i0 = base + sub;
        int i1 = i0 + 4;
        int i2 = i0 + 8;
        int i3 = i0 + 12;
        int c0 = (i0 < e) ? i0 : (e - 1);   // e > base >= s here, so e-1 valid
        int c1 = (i1 < e) ? i1 : (e - 1);
        int c2 = (i2 < e) ? i2 : (e - 1);
        int c3 = (i3 < e) ? i3 : (e - 1);
        float m0 = (i0 < e) ? 1.f : 0.f;
        float m1 = (i1 < e) ? 1.f : 0.f;
        float m2 = (i2 < e) ? 1.f : 0.f;
        float m3 = (i3 < e) ? 1.f : 0.f;
        int n0 = neigh_idx[c0];
        int n1 = neigh_idx[c1];
        int n2 = neigh_idx[c2];
        int n3 = neigh_idx[c3];
        float4 v0 = reinterpret_cast<const float4*>(feat + (size_t)n0 * D_FEAT)[chunk];
        float4 v1 = reinterpret_cast<const float4*>(feat + (size_t)n1 * D_FEAT)[chunk];
        float4 v2 = reinterpret_cast<const float4*>(feat + (size_t)n2 * D_FEAT)[chunk];
        float4 v3 = reinterpret_cast<const float4*>(feat + (size_t)n3 * D_FEAT)[chunk];
        a0.x = fmaf(m0, v0.x, a0.x); a0.y = fmaf(m0, v0.y, a0.y);
        a0.z = fmaf(m0, v0.z, a0.z); a0.w = fmaf(m0, v0.w, a0.w);
        a1.x = fmaf(m1, v1.x, a1.x); a1.y = fmaf(m1, v1.y, a1.y);
        a1.z = fmaf(m1, v1.z, a1.z); a1.w = fmaf(m1, v1.w, a1.w);
        a2.x = fmaf(m2, v2.x, a2.x); a2.y = fmaf(m2, v2.y, a2.y);
        a2.z = fmaf(m2, v2.z, a2.z); a2.w = fmaf(m2, v2.w, a2.w);
        a3.x = fmaf(m3, v3.x, a3.x); a3.y = fmaf(m3, v3.y, a3.y);
        a3.z = fmaf(m3, v3.z, a3.z); a3.w = fmaf(m3, v3.w, a3.w);
    }

    float4 acc;
    acc.x = (a0.x + a1.x) + (a2.x + a3.x);
    acc.y = (a0.y + a1.y) + (a2.y + a3.y);
    acc.z = (a0.z + a1.z) + (a2.z + a3.z);
    acc.w = (a0.w + a1.w) + (a2.w + a3.w);

    // reduce across the 4 subgroups (lanes l, l^16, l^32, l^48)
    acc.x += __shfl_xor(acc.x, 16);
    acc.y += __shfl_xor(acc.y, 16);
    acc.z += __shfl_xor(acc.z, 16);
    acc.w += __shfl_xor(acc.w, 16);
    acc.x += __shfl_xor(acc.x, 32);
    acc.y += __shfl_xor(acc.y, 32);
    acc.z += __shfl_xor(acc.z, 32);
    acc.w += __shfl_xor(acc.w, 32);

    if (lane < 16) {
        reinterpret_cast<float4*>(out + (size_t)node * D_FEAT)[chunk] = acc;
    }
}

extern "C" void kernel_launch(void* const* d_in, const int* in_sizes, int n_in,
                              void* d_out, int out_size, void* d_ws, size_t ws_size,
                              hipStream_t stream) {
    const float* features  = (const float*)d_in[0];
    const int*   neigh_idx = (const int*)d_in[1];
    const int*   seg_ids   = (const int*)d_in[2];
    float*       out       = (float*)d_out;
    int*         offsets   = (int*)d_ws;  // (N_NODES+1) * 4 bytes

    {
        int total = N_NODES + 1;
        int block = 256;
        int grid  = (total + block - 1) / block;
        seg_offsets_kernel<<<grid, block, 0, stream>>>(seg_ids, offsets);
    }
    {
        int block = 256;                 // 4 waves = 4 nodes per block
        int grid  = (N_NODES + 3) / 4;
        aggregate_kernel<<<grid, block, 0, stream>>>(features, neigh_idx, offsets, out);
    }
}

// Round 5
// 54.413 us; speedup vs baseline: 3.7472x; 1.2174x over previous
//
#include <hip/hip_runtime.h>
#include <hip/hip_bf16.h>

#define N_NODES 100000
#define N_EDGES 1600000
#define D_FEAT  64

// d_ws layout: [offsets (N_NODES+1) ints, padded to 1KB] [bf16 feature table]
#define OFF_WS_BYTES  ((((N_NODES + 1) * 4) + 1023) & ~1023)
#define BF16_WS_BYTES ((size_t)N_NODES * D_FEAT * 2)

// Kernel 1 (proven): offsets[n] = first edge i with seg_ids[i] >= n.
__global__ void seg_offsets_kernel(const int* __restrict__ seg_ids,
                                   int* __restrict__ offsets) {
    int n = blockIdx.x * blockDim.x + threadIdx.x;
    if (n > N_NODES) return;
    int lo = 0, hi = N_EDGES;
    while (lo < hi) {
        int mid = (lo + hi) >> 1;
        if (seg_ids[mid] < n) lo = mid + 1; else hi = mid;
    }
    offsets[n] = lo;
}

// Kernel 1b: f32 -> bf16 (RNE) feature table into workspace. Streaming,
// fully coalesced: float4 in, ushort4 out. Deterministic.
__global__ __launch_bounds__(256) void convert_bf16_kernel(
        const float* __restrict__ feat, ushort* __restrict__ fb) {
    const int total = N_NODES * D_FEAT / 4;   // groups of 4 floats
    for (int i = blockIdx.x * blockDim.x + threadIdx.x; i < total;
         i += gridDim.x * blockDim.x) {
        float4 v = reinterpret_cast<const float4*>(feat)[i];
        uint ux = __float_as_uint(v.x), uy = __float_as_uint(v.y);
        uint uz = __float_as_uint(v.z), uw = __float_as_uint(v.w);
        ushort4 o;
        o.x = (ushort)((ux + 0x7fffu + ((ux >> 16) & 1u)) >> 16);
        o.y = (ushort)((uy + 0x7fffu + ((uy >> 16) & 1u)) >> 16);
        o.z = (ushort)((uz + 0x7fffu + ((uz >> 16) & 1u)) >> 16);
        o.w = (ushort)((uw + 0x7fffu + ((uw >> 16) & 1u)) >> 16);
        reinterpret_cast<ushort4*>(fb)[i] = o;
    }
}

// Kernel 2 (bf16 path): wave-per-node.
//   - one wave-wide load stages up to 64 edge indices in registers
//     (my_idx = neigh_idx[s + lane]); the gather loop gets indices via
//     __shfl (register bpermute) -> no memory dependency before the row load.
//   - sub = lane>>4 picks the edge slot, chunk = lane&15 picks the 8-byte
//     bf16 chunk (4 values). 4 slots x unroll(16 edges/iter) as in round 4.
//   - rows are 128B (bf16) -> half the gather traffic of f32.
//   - f32 accumulate, shfl_xor(16,32) reduce, lanes 0-15 store float4 (256B).
// No atomics, disjoint writes -> deterministic.
__global__ __launch_bounds__(256) void aggregate_bf16_kernel(
        const ushort* __restrict__ fb,
        const int* __restrict__ neigh_idx,
        const int* __restrict__ offsets,
        float* __restrict__ out) {
    int node  = blockIdx.x * 4 + (threadIdx.x >> 6);   // wave-uniform
    if (node >= N_NODES) return;
    int lane  = threadIdx.x & 63;
    int sub   = lane >> 4;
    int chunk = lane & 15;

    int s = offsets[node];
    int e = offsets[node + 1];

    float4 a0 = make_float4(0.f, 0.f, 0.f, 0.f);
    float4 a1 = make_float4(0.f, 0.f, 0.f, 0.f);
    float4 a2 = make_float4(0.f, 0.f, 0.f, 0.f);
    float4 a3 = make_float4(0.f, 0.f, 0.f, 0.f);

    for (int cb = s; cb < e; cb += 64) {           // 64-edge chunks (usually 1)
        int li = cb + lane;
        int ci = (li < e) ? li : (e - 1);          // e > s here, e-1 valid
        int my_idx = neigh_idx[ci];                // 1 coalesced load / chunk
        int lim = e - cb; if (lim > 64) lim = 64;  // edges in this chunk

        for (int p = 0; p < lim; p += 16) {
            int p0 = p + sub, p1 = p0 + 4, p2 = p0 + 8, p3 = p0 + 12;
            int q0 = (p0 < lim) ? p0 : (lim - 1);
            int q1 = (p1 < lim) ? p1 : (lim - 1);
            int q2 = (p2 < lim) ? p2 : (lim - 1);
            int q3 = (p3 < lim) ? p3 : (lim - 1);
            float m0 = (p0 < lim) ? 1.f : 0.f;
            float m1 = (p1 < lim) ? 1.f : 0.f;
            float m2 = (p2 < lim) ? 1.f : 0.f;
            float m3 = (p3 < lim) ? 1.f : 0.f;
            int n0 = __shfl(my_idx, q0);
            int n1 = __shfl(my_idx, q1);
            int n2 = __shfl(my_idx, q2);
            int n3 = __shfl(my_idx, q3);
            uint2 w0 = reinterpret_cast<const uint2*>(fb + (size_t)n0 * D_FEAT)[chunk];
            uint2 w1 = reinterpret_cast<const uint2*>(fb + (size_t)n1 * D_FEAT)[chunk];
            uint2 w2 = reinterpret_cast<const uint2*>(fb + (size_t)n2 * D_FEAT)[chunk];
            uint2 w3 = reinterpret_cast<const uint2*>(fb + (size_t)n3 * D_FEAT)[chunk];
            a0.x = fmaf(m0, __uint_as_float(w0.x << 16), a0.x);
            a0.y = fmaf(m0, __uint_as_float(w0.x & 0xFFFF0000u), a0.y);
            a0.z = fmaf(m0, __uint_as_float(w0.y << 16), a0.z);
            a0.w = fmaf(m0, __uint_as_float(w0.y & 0xFFFF0000u), a0.w);
            a1.x = fmaf(m1, __uint_as_float(w1.x << 16), a1.x);
            a1.y = fmaf(m1, __uint_as_float(w1.x & 0xFFFF0000u), a1.y);
            a1.z = fmaf(m1, __uint_as_float(w1.y << 16), a1.z);
            a1.w = fmaf(m1, __uint_as_float(w1.y & 0xFFFF0000u), a1.w);
            a2.x = fmaf(m2, __uint_as_float(w2.x << 16), a2.x);
            a2.y = fmaf(m2, __uint_as_float(w2.x & 0xFFFF0000u), a2.y);
            a2.z = fmaf(m2, __uint_as_float(w2.y << 16), a2.z);
            a2.w = fmaf(m2, __uint_as_float(w2.y & 0xFFFF0000u), a2.w);
            a3.x = fmaf(m3, __uint_as_float(w3.x << 16), a3.x);
            a3.y = fmaf(m3, __uint_as_float(w3.x & 0xFFFF0000u), a3.y);
            a3.z = fmaf(m3, __uint_as_float(w3.y << 16), a3.z);
            a3.w = fmaf(m3, __uint_as_float(w3.y & 0xFFFF0000u), a3.w);
        }
    }

    float4 acc;
    acc.x = (a0.x + a1.x) + (a2.x + a3.x);
    acc.y = (a0.y + a1.y) + (a2.y + a3.y);
    acc.z = (a0.z + a1.z) + (a2.z + a3.z);
    acc.w = (a0.w + a1.w) + (a2.w + a3.w);

    acc.x += __shfl_xor(acc.x, 16);
    acc.y += __shfl_xor(acc.y, 16);
    acc.z += __shfl_xor(acc.z, 16);
    acc.w += __shfl_xor(acc.w, 16);
    acc.x += __shfl_xor(acc.x, 32);
    acc.y += __shfl_xor(acc.y, 32);
    acc.z += __shfl_xor(acc.z, 32);
    acc.w += __shfl_xor(acc.w, 32);

    if (lane < 16) {
        // lane l (l<16): chunk=l holds elements 4l..4l+3 of the row
        reinterpret_cast<float4*>(out + (size_t)node * D_FEAT)[chunk] = acc;
    }
}

// Fallback aggregate (round-4, f32 gather) if ws can't hold the bf16 table.
__global__ __launch_bounds__(256) void aggregate_kernel(
        const float* __restrict__ feat,
        const int* __restrict__ neigh_idx,
        const int* __restrict__ offsets,
        float* __restrict__ out) {
    int node  = blockIdx.x * 4 + (threadIdx.x >> 6);
    if (node >= N_NODES) return;
    int lane  = threadIdx.x & 63;
    int sub   = lane >> 4;
    int chunk = lane & 15;

    int s = offsets[node];
    int e = offsets[node + 1];

    float4 a0 = make_float4(0.f, 0.f, 0.f, 0.f);
    float4 a1 = make_float4(0.f, 0.f, 0.f, 0.f);
    float4 a2 = make_float4(0.f, 0.f, 0.f, 0.f);
    float4 a3 = make_float4(0.f, 0.f, 0.f, 0.f);

    for (int base = s; base < e; base += 16) {
        int i0 = base + sub, i1 = i0 + 4, i2 = i0 + 8, i3 = i0 + 12;
        int c0 = (i0 < e) ? i0 : (e - 1);
        int c1 = (i1 < e) ? i1 : (e - 1);
        int c2 = (i2 < e) ? i2 : (e - 1);
        int c3 = (i3 < e) ? i3 : (e - 1);
        float m0 = (i0 < e) ? 1.f : 0.f;
        float m1 = (i1 < e) ? 1.f : 0.f;
        float m2 = (i2 < e) ? 1.f : 0.f;
        float m3 = (i3 < e) ? 1.f : 0.f;
        int n0 = neigh_idx[c0], n1 = neigh_idx[c1];
        int n2 = neigh_idx[c2], n3 = neigh_idx[c3];
        float4 v0 = reinterpret_cast<const float4*>(feat + (size_t)n0 * D_FEAT)[chunk];
        float4 v1 = reinterpret_cast<const float4*>(feat + (size_t)n1 * D_FEAT)[chunk];
        float4 v2 = reinterpret_cast<const float4*>(feat + (size_t)n2 * D_FEAT)[chunk];
        float4 v3 = reinterpret_cast<const float4*>(feat + (size_t)n3 * D_FEAT)[chunk];
        a0.x = fmaf(m0, v0.x, a0.x); a0.y = fmaf(m0, v0.y, a0.y);
        a0.z = fmaf(m0, v0.z, a0.z); a0.w = fmaf(m0, v0.w, a0.w);
        a1.x = fmaf(m1, v1.x, a1.x); a1.y = fmaf(m1, v1.y, a1.y);
        a1.z = fmaf(m1, v1.z, a1.z); a1.w = fmaf(m1, v1.w, a1.w);
        a2.x = fmaf(m2, v2.x, a2.x); a2.y = fmaf(m2, v2.y, a2.y);
        a2.z = fmaf(m2, v2.z, a2.z); a2.w = fmaf(m2, v2.w, a2.w);
        a3.x = fmaf(m3, v3.x, a3.x); a3.y = fmaf(m3, v3.y, a3.y);
        a3.z = fmaf(m3, v3.z, a3.z); a3.w = fmaf(m3, v3.w, a3.w);
    }

    float4 acc;
    acc.x = (a0.x + a1.x) + (a2.x + a3.x);
    acc.y = (a0.y + a1.y) + (a2.y + a3.y);
    acc.z = (a0.z + a1.z) + (a2.z + a3.z);
    acc.w = (a0.w + a1.w) + (a2.w + a3.w);

    acc.x += __shfl_xor(acc.x, 16);
    acc.y += __shfl_xor(acc.y, 16);
    acc.z += __shfl_xor(acc.z, 16);
    acc.w += __shfl_xor(acc.w, 16);
    acc.x += __shfl_xor(acc.x, 32);
    acc.y += __shfl_xor(acc.y, 32);
    acc.z += __shfl_xor(acc.z, 32);
    acc.w += __shfl_xor(acc.w, 32);

    if (lane < 16) {
        reinterpret_cast<float4*>(out + (size_t)node * D_FEAT)[chunk] = acc;
    }
}

extern "C" void kernel_launch(void* const* d_in, const int* in_sizes, int n_in,
                              void* d_out, int out_size, void* d_ws, size_t ws_size,
                              hipStream_t stream) {
    const float* features  = (const float*)d_in[0];
    const int*   neigh_idx = (const int*)d_in[1];
    const int*   seg_ids   = (const int*)d_in[2];
    float*       out       = (float*)d_out;
    int*         offsets   = (int*)d_ws;

    {
        int total = N_NODES + 1;
        int block = 256;
        int grid  = (total + block - 1) / block;
        seg_offsets_kernel<<<grid, block, 0, stream>>>(seg_ids, offsets);
    }

    bool bf16_path = (ws_size >= (size_t)OFF_WS_BYTES + BF16_WS_BYTES);
    if (bf16_path) {
        ushort* fb = (ushort*)((char*)d_ws + OFF_WS_BYTES);
        convert_bf16_kernel<<<2048, 256, 0, stream>>>(features, fb);
        int block = 256;                 // 4 waves = 4 nodes per block
        int grid  = (N_NODES + 3) / 4;
        aggregate_bf16_kernel<<<grid, block, 0, stream>>>(fb, neigh_idx, offsets, out);
    } else {
        int block = 256;
        int grid  = (N_NODES + 3) / 4;
        aggregate_kernel<<<grid, block, 0, stream>>>(features, neigh_idx, offsets, out);
    }
}

// Round 6
// 51.607 us; speedup vs baseline: 3.9510x; 1.0544x over previous
//
#include <hip/hip_runtime.h>
#include <hip/hip_bf16.h>

#define N_NODES 100000
#define N_EDGES 1600000
#define D_FEAT  64

// d_ws layout: [offsets (N_NODES+1) ints, padded to 1KB] [bf16 feature table]
#define OFF_WS_BYTES   ((((N_NODES + 1) * 4) + 1023) & ~1023)
#define BF16_WS_BYTES  ((size_t)N_NODES * D_FEAT * 2)
#define OFFSET_BLOCKS  ((N_NODES + 1 + 255) / 256)
#define CONVERT_BLOCKS 2048

// Fused prep: blocks [0, OFFSET_BLOCKS) compute offsets via binary search
// (proven in rounds 1/4/5); blocks [OFFSET_BLOCKS, +CONVERT_BLOCKS) convert
// features f32 -> bf16 (RNE) into the workspace table. The two halves touch
// disjoint data and run concurrently in one dispatch.
__global__ __launch_bounds__(256) void prep_kernel(
        const float* __restrict__ feat,
        const int* __restrict__ seg_ids,
        int* __restrict__ offsets,
        ushort* __restrict__ fb) {
    int b = blockIdx.x;
    if (b < OFFSET_BLOCKS) {
        int n = b * 256 + threadIdx.x;
        if (n > N_NODES) return;
        int lo = 0, hi = N_EDGES;
        while (lo < hi) {
            int mid = (lo + hi) >> 1;
            if (seg_ids[mid] < n) lo = mid + 1; else hi = mid;
        }
        offsets[n] = lo;
    } else {
        const int total = N_NODES * D_FEAT / 4;   // float4 groups
        int tid = (b - OFFSET_BLOCKS) * 256 + threadIdx.x;
        for (int i = tid; i < total; i += CONVERT_BLOCKS * 256) {
            float4 v = reinterpret_cast<const float4*>(feat)[i];
            uint ux = __float_as_uint(v.x), uy = __float_as_uint(v.y);
            uint uz = __float_as_uint(v.z), uw = __float_as_uint(v.w);
            ushort4 o;
            o.x = (ushort)((ux + 0x7fffu + ((ux >> 16) & 1u)) >> 16);
            o.y = (ushort)((uy + 0x7fffu + ((uy >> 16) & 1u)) >> 16);
            o.z = (ushort)((uz + 0x7fffu + ((uz >> 16) & 1u)) >> 16);
            o.w = (ushort)((uw + 0x7fffu + ((uw >> 16) & 1u)) >> 16);
            reinterpret_cast<ushort4*>(fb)[i] = o;
        }
    }
}

// Aggregate (bf16, uint4 gathers): wave-per-node.
//   slot = lane>>3 (0..7): edge slot; ch = lane&7: which 16B uint4 of the
//   128B bf16 row. One load instruction = 64 lanes x 16B = 8 rows.
//   Indices staged wave-wide (neigh_idx[cb+lane]) then distributed via __shfl
//   (register-only) -> gathers issue back-to-back. 2 loads in flight per lane
//   per iter (16 edges/iter = avg segment). Tail via clamped idx + masked FMA.
//   Reduce across 8 slots: shfl_xor(8,16,32); lanes 0-7 store 32B each.
// Disjoint writes, no atomics -> deterministic across replays.
__global__ __launch_bounds__(256) void aggregate_bf16_kernel(
        const ushort* __restrict__ fb,
        const int* __restrict__ neigh_idx,
        const int* __restrict__ offsets,
        float* __restrict__ out) {
    int node = blockIdx.x * 4 + (threadIdx.x >> 6);   // wave-uniform
    if (node >= N_NODES) return;
    int lane = threadIdx.x & 63;
    int slot = lane >> 3;
    int ch   = lane & 7;

    int s = offsets[node];
    int e = offsets[node + 1];

    float a0[8], a1[8];
    #pragma unroll
    for (int k = 0; k < 8; ++k) { a0[k] = 0.f; a1[k] = 0.f; }

    for (int cb = s; cb < e; cb += 64) {           // 64-edge chunks (usually 1)
        int li = cb + lane;
        int ci = (li < e) ? li : (e - 1);          // loop entered => e-1 >= s
        int my_idx = neigh_idx[ci];                // 1 coalesced load / chunk
        int lim = e - cb; if (lim > 64) lim = 64;

        for (int p = 0; p < lim; p += 16) {
            int p0 = p + slot, p1 = p0 + 8;
            int q0 = (p0 < lim) ? p0 : (lim - 1);
            int q1 = (p1 < lim) ? p1 : (lim - 1);
            float m0 = (p0 < lim) ? 1.f : 0.f;
            float m1 = (p1 < lim) ? 1.f : 0.f;
            int n0 = __shfl(my_idx, q0);
            int n1 = __shfl(my_idx, q1);
            uint4 w0 = reinterpret_cast<const uint4*>(fb + (size_t)n0 * D_FEAT)[ch];
            uint4 w1 = reinterpret_cast<const uint4*>(fb + (size_t)n1 * D_FEAT)[ch];
            a0[0] = fmaf(m0, __uint_as_float(w0.x << 16),         a0[0]);
            a0[1] = fmaf(m0, __uint_as_float(w0.x & 0xFFFF0000u), a0[1]);
            a0[2] = fmaf(m0, __uint_as_float(w0.y << 16),         a0[2]);
            a0[3] = fmaf(m0, __uint_as_float(w0.y & 0xFFFF0000u), a0[3]);
            a0[4] = fmaf(m0, __uint_as_float(w0.z << 16),         a0[4]);
            a0[5] = fmaf(m0, __uint_as_float(w0.z & 0xFFFF0000u), a0[5]);
            a0[6] = fmaf(m0, __uint_as_float(w0.w << 16),         a0[6]);
            a0[7] = fmaf(m0, __uint_as_float(w0.w & 0xFFFF0000u), a0[7]);
            a1[0] = fmaf(m1, __uint_as_float(w1.x << 16),         a1[0]);
            a1[1] = fmaf(m1, __uint_as_float(w1.x & 0xFFFF0000u), a1[1]);
            a1[2] = fmaf(m1, __uint_as_float(w1.y << 16),         a1[2]);
            a1[3] = fmaf(m1, __uint_as_float(w1.y & 0xFFFF0000u), a1[3]);
            a1[4] = fmaf(m1, __uint_as_float(w1.z << 16),         a1[4]);
            a1[5] = fmaf(m1, __uint_as_float(w1.z & 0xFFFF0000u), a1[5]);
            a1[6] = fmaf(m1, __uint_as_float(w1.w << 16),         a1[6]);
            a1[7] = fmaf(m1, __uint_as_float(w1.w & 0xFFFF0000u), a1[7]);
        }
    }

    float r[8];
    #pragma unroll
    for (int k = 0; k < 8; ++k) r[k] = a0[k] + a1[k];
    #pragma unroll
    for (int k = 0; k < 8; ++k) {
        r[k] += __shfl_xor(r[k], 8);
        r[k] += __shfl_xor(r[k], 16);
        r[k] += __shfl_xor(r[k], 32);
    }

    if (lane < 8) {
        float4* orow = reinterpret_cast<float4*>(out + (size_t)node * D_FEAT);
        orow[2 * ch]     = make_float4(r[0], r[1], r[2], r[3]);
        orow[2 * ch + 1] = make_float4(r[4], r[5], r[6], r[7]);
    }
}

// Fallback (round-4 f32 path) if ws can't hold the bf16 table.
__global__ __launch_bounds__(256) void aggregate_kernel(
        const float* __restrict__ feat,
        const int* __restrict__ neigh_idx,
        const int* __restrict__ offsets,
        float* __restrict__ out) {
    int node  = blockIdx.x * 4 + (threadIdx.x >> 6);
    if (node >= N_NODES) return;
    int lane  = threadIdx.x & 63;
    int sub   = lane >> 4;
    int chunk = lane & 15;

    int s = offsets[node];
    int e = offsets[node + 1];

    float4 a0 = make_float4(0.f, 0.f, 0.f, 0.f);
    float4 a1 = make_float4(0.f, 0.f, 0.f, 0.f);

    for (int base = s; base < e; base += 8) {
        int i0 = base + sub, i1 = i0 + 4;
        int c0 = (i0 < e) ? i0 : (e - 1);
        int c1 = (i1 < e) ? i1 : (e - 1);
        float m0 = (i0 < e) ? 1.f : 0.f;
        float m1 = (i1 < e) ? 1.f : 0.f;
        int n0 = neigh_idx[c0], n1 = neigh_idx[c1];
        float4 v0 = reinterpret_cast<const float4*>(feat + (size_t)n0 * D_FEAT)[chunk];
        float4 v1 = reinterpret_cast<const float4*>(feat + (size_t)n1 * D_FEAT)[chunk];
        a0.x = fmaf(m0, v0.x, a0.x); a0.y = fmaf(m0, v0.y, a0.y);
        a0.z = fmaf(m0, v0.z, a0.z); a0.w = fmaf(m0, v0.w, a0.w);
        a1.x = fmaf(m1, v1.x, a1.x); a1.y = fmaf(m1, v1.y, a1.y);
        a1.z = fmaf(m1, v1.z, a1.z); a1.w = fmaf(m1, v1.w, a1.w);
    }

    float4 acc;
    acc.x = a0.x + a1.x; acc.y = a0.y + a1.y;
    acc.z = a0.z + a1.z; acc.w = a0.w + a1.w;
    acc.x += __shfl_xor(acc.x, 16); acc.y += __shfl_xor(acc.y, 16);
    acc.z += __shfl_xor(acc.z, 16); acc.w += __shfl_xor(acc.w, 16);
    acc.x += __shfl_xor(acc.x, 32); acc.y += __shfl_xor(acc.y, 32);
    acc.z += __shfl_xor(acc.z, 32); acc.w += __shfl_xor(acc.w, 32);

    if (lane < 16) {
        reinterpret_cast<float4*>(out + (size_t)node * D_FEAT)[chunk] = acc;
    }
}

extern "C" void kernel_launch(void* const* d_in, const int* in_sizes, int n_in,
                              void* d_out, int out_size, void* d_ws, size_t ws_size,
                              hipStream_t stream) {
    const float* features  = (const float*)d_in[0];
    const int*   neigh_idx = (const int*)d_in[1];
    const int*   seg_ids   = (const int*)d_in[2];
    float*       out       = (float*)d_out;
    int*         offsets   = (int*)d_ws;

    bool bf16_path = (ws_size >= (size_t)OFF_WS_BYTES + BF16_WS_BYTES);
    if (bf16_path) {
        ushort* fb = (ushort*)((char*)d_ws + OFF_WS_BYTES);
        prep_kernel<<<OFFSET_BLOCKS + CONVERT_BLOCKS, 256, 0, stream>>>(
            features, seg_ids, offsets, fb);
        int grid = (N_NODES + 3) / 4;          // 4 waves = 4 nodes per block
        aggregate_bf16_kernel<<<grid, 256, 0, stream>>>(fb, neigh_idx, offsets, out);
    } else {
        int total = N_NODES + 1;
        int grid1 = (total + 255) / 256;
        // offsets-only prep (reuse prep_kernel's search half via same code path)
        prep_kernel<<<grid1 < OFFSET_BLOCKS ? grid1 : OFFSET_BLOCKS, 256, 0, stream>>>(
            features, seg_ids, offsets, (ushort*)nullptr);
        int grid = (N_NODES + 3) / 4;
        aggregate_kernel<<<grid, 256, 0, stream>>>(features, neigh_idx, offsets, out);
    }
}